// Round 7
// baseline (285.751 us; speedup 1.0000x reference)
//
#include <hip/hip_runtime.h>
#include <math.h>

// (B,N,D,H) = (2,2048,1024,16), HD=64, ROT=32
#define NN 2048
#define DD 1024
#define HH 16
#define OUTSZ (2*NN*DD)

typedef unsigned short u16;
typedef unsigned int u32;
typedef __attribute__((ext_vector_type(8))) short short8;     // 8 bf16 (4 VGPRs)
typedef __attribute__((ext_vector_type(4))) float floatx4;
typedef __attribute__((ext_vector_type(4))) unsigned short us4;

__device__ __forceinline__ u16 f2bf(float x) {
    union { float f; unsigned u; } v; v.f = x;
    unsigned r = v.u + 0x7FFFu + ((v.u >> 16) & 1u);   // RNE
    return (u16)(r >> 16);
}

__device__ __forceinline__ u32 fbits(float x) {
    union { float f; u32 u; } v; v.f = x; return v.u;
}

// pack two fp32 -> two bf16 (round-half-up) in one v_perm
__device__ __forceinline__ u32 pack_bf2(float lo, float hi) {
    return __builtin_amdgcn_perm(fbits(hi) + 0x8000u, fbits(lo) + 0x8000u, 0x07060302u);
}

__device__ __forceinline__ float fexp2(float x) {
#if __has_builtin(__builtin_amdgcn_exp2f)
    return __builtin_amdgcn_exp2f(x);
#else
    return __expf(x * 0.69314718056f);
#endif
}

__device__ __forceinline__ void gl_lds16(const u16* g, u16* l) {
    __builtin_amdgcn_global_load_lds(
        (const __attribute__((address_space(1))) unsigned int*)g,
        (__attribute__((address_space(3))) unsigned int*)l, 16, 0, 0);
}

// ---------------------------------------------------------------------------
// fp32 -> bf16 cast for q,k,v + 4 weights
// ---------------------------------------------------------------------------
struct CastArgs { const float* s[7]; u16* d[7]; int n[7]; };

__global__ __launch_bounds__(256)
void cast_bf16(CastArgs a) {
    const int ten = blockIdx.y;
    const float4* s = (const float4*)a.s[ten];
    us4* d = (us4*)a.d[ten];
    const int n4 = a.n[ten] >> 2;
    for (int i = blockIdx.x * 256 + threadIdx.x; i < n4; i += gridDim.x * 256) {
        float4 f = s[i];
        us4 u = {f2bf(f.x), f2bf(f.y), f2bf(f.z), f2bf(f.w)};
        d[i] = u;
    }
}

// ---------------------------------------------------------------------------
// bf16 MFMA projection GEMM (unchanged from R6): tile 128 x TN, BK=64.
// ---------------------------------------------------------------------------
struct ProjArgs {
    const u16* X[4]; const u16* W[4];
    float* outf[4];  u16* outb[4];
    const float* rot;
};

template<int TN>
__global__ __launch_bounds__(256)
void mfma_proj(ProjArgs a, int mode_base)
{
    constexpr int TNW = TN / 2;      // wave cols
    constexpr int NJ  = TNW / 16;    // B-fragments per wave

    __shared__ __align__(16) u16 As[128 * 64];
    __shared__ __align__(16) u16 Bs[TN * 64];

    const int mode = mode_base + blockIdx.z;
    const u16* __restrict__ X   = a.X[mode];
    const u16* __restrict__ Wm  = a.W[mode];
    float* __restrict__ outf    = a.outf[mode];
    u16* __restrict__ outb      = a.outb[mode];
    const float* __restrict__ rot = a.rot;

    const int t    = threadIdx.x;
    const int lane = t & 63;
    const int w    = t >> 6;
    const int wr   = (w >> 1) * 64;
    const int wc   = (w & 1) * TNW;
    const int m0   = blockIdx.y * 128;
    const int j0   = blockIdx.x * TN;

    const int lc = (t & 7) ^ ((t >> 3) & 7);
    const u16* gA = X  + (size_t)(m0 + (t >> 3)) * DD + lc * 8;
    const u16* gB = Wm + (size_t)(j0 + (t >> 3)) * DD + lc * 8;

    const int fr = lane & 15;
    const int fq = lane >> 4;

    floatx4 acc[4][NJ] = {};

    for (int k0 = 0; k0 < DD; k0 += 64) {
        __syncthreads();
        #pragma unroll
        for (int p = 0; p < 4; ++p)
            gl_lds16(gA + (size_t)(32 * p) * DD + k0, As + (p * 256 + t) * 8);
        #pragma unroll
        for (int p = 0; p < TN / 32; ++p)
            gl_lds16(gB + (size_t)(32 * p) * DD + k0, Bs + (p * 256 + t) * 8);
        __syncthreads();
        #pragma unroll
        for (int kk = 0; kk < 2; ++kk) {
            const int ph = (kk * 4 + fq) ^ (fr & 7);
            short8 af[4], bf[NJ];
            #pragma unroll
            for (int i = 0; i < 4; ++i)
                af[i] = *(const short8*)(As + (wr + i * 16 + fr) * 64 + ph * 8);
            #pragma unroll
            for (int j = 0; j < NJ; ++j)
                bf[j] = *(const short8*)(Bs + (wc + j * 16 + fr) * 64 + ph * 8);
            #pragma unroll
            for (int i = 0; i < 4; ++i)
                #pragma unroll
                for (int j = 0; j < NJ; ++j)
                    acc[i][j] = __builtin_amdgcn_mfma_f32_16x16x32_bf16(af[i], bf[j], acc[i][j], 0, 0, 0);
        }
    }

    const int b = m0 >> 11;
    #pragma unroll
    for (int i = 0; i < 4; ++i) {
        const int mrow  = m0 + wr + i * 16 + fq * 4;   // + r
        const int nbase = mrow & (NN - 1);
        #pragma unroll
        for (int j = 0; j < NJ; ++j) {
            const int col = j0 + wc + j * 16 + fr;
            const int h = col >> 6, d = col & 63;
            const int bh = b * HH + h;
            float v[4];
            #pragma unroll
            for (int r = 0; r < 4; ++r) v[r] = acc[i][j][r];
            // rotary applies to head-dims d<32; d = ((wc+j*16)&63) + fr
            if (mode <= 1 && ((wc + j * 16) & 63) < 32) {
                #pragma unroll
                for (int r = 0; r < 4; ++r) {
                    const int n = nbase + r;
                    float c = v[r];
                    float p = __shfl_xor(c, 1);     // partner element d^1
                    float f = rot[n * 32 + d];
                    float sn, cs; __sincosf(f, &sn, &cs);
                    v[r] = (d & 1) ? fmaf(c, cs, p * sn) : fmaf(c, cs, -p * sn);
                }
            }
            if (mode == 0) {
                // fold softmax scale 1/8 and log2(e) into Q
                #pragma unroll
                for (int r = 0; r < 4; ++r)
                    outb[((size_t)bh * NN + nbase + r) * 64 + d] = f2bf(v[r] * 0.1803368801111244f);
            } else if (mode == 1) {
                float4 f4 = {v[0], v[1], v[2], v[3]};
                *(float4*)&outf[((size_t)bh * 64 + d) * NN + nbase] = f4;
                #pragma unroll
                for (int r = 0; r < 4; ++r)
                    outb[((size_t)bh * NN + nbase + r) * 64 + d] = f2bf(v[r]);
            } else if (mode == 2) {
                #pragma unroll
                for (int r = 0; r < 4; ++r)
                    outf[((size_t)bh * NN + nbase + r) * 64 + d] = v[r];
                us4 u = {f2bf(v[0]), f2bf(v[1]), f2bf(v[2]), f2bf(v[3])};
                *(us4*)&outb[((size_t)bh * 64 + d) * NN + nbase] = u;
            } else {
                #pragma unroll
                for (int r = 0; r < 4; ++r)
                    outf[(size_t)(mrow + r) * DD + col] = v[r];
            }
        }
    }
}

// ---------------------------------------------------------------------------
// bf16 MFMA flash attention, barrier-free K-loop.
// Block = (b,h) x 64 queries; grid (bh, qtile): same-head blocks pin to one
// XCD (stride 32 % 8 == 0) so K/V are L2-resident (verified R6: FETCH 12 MB).
// K/V MFMA fragments load DIRECTLY global->VGPR (contiguous 16 B per lane in
// kh (B,H,N,HD) / vt (B,H,HD,N)) -- no K/V LDS, no __syncthreads in the loop.
// Hand-pipelined: next iter's K/V frags prefetched during softmax+PV.
// LDS only holds the per-wave P tile (same-wave, program-order) + final
// cross-wave O/l reduction scratch.
// ---------------------------------------------------------------------------
__global__ __launch_bounds__(256, 3)
void mfma_attn(const u16* __restrict__ qh, const u16* __restrict__ kh,
               const u16* __restrict__ vt, u16* __restrict__ ctx)
{
    __shared__ __align__(16) u16 Ps[4 * 64 * 40];   // per-wave P, 80-B rows, 20 KB
    __shared__ float Lsc[64];

    const int t    = threadIdx.x;
    const int lane = t & 63;
    const int w    = t >> 6;
    const int fr   = lane & 15;
    const int fq   = lane >> 4;
    const int bh   = blockIdx.x;
    const int q0   = blockIdx.y * 64;
    const int b    = bh >> 4, h = bh & 15;

    // Q: all 64 queries per wave (B-frag: n=query=fr, k=kk*32+fq*8)
    short8 qf[4][2];
    #pragma unroll
    for (int c = 0; c < 4; ++c)
        #pragma unroll
        for (int kk = 0; kk < 2; ++kk)
            qf[c][kk] = *(const short8*)(qh +
                ((size_t)bh * NN + q0 + c * 16 + fr) * 64 + kk * 32 + fq * 8);

    // per-lane fragment base pointers
    // K A-frag: row = j0k + w*32 + jt*16 + fr, k-chunk = kk*32 + fq*8
    const u16* kA = kh + ((size_t)bh * NN + w * 32 + fr) * 64 + fq * 8;
    // V B-frag: n = d = 16n + fr, k = key = j0k + w*32 + fq*8
    const u16* vB = vt + ((size_t)bh * 64 + fr) * NN + w * 32 + fq * 8;

    u16* Pw = Ps + w * 64 * 40;                  // this wave's 64q x 32k tile

    floatx4 o4[4][4] = {};                       // [query m-tile][d n-tile]
    float lrun[4] = {0.f, 0.f, 0.f, 0.f};

    // prefetch iter-0 fragments
    short8 kf[2][2], vf[4];
    #pragma unroll
    for (int jt = 0; jt < 2; ++jt)
        #pragma unroll
        for (int kk = 0; kk < 2; ++kk)
            kf[jt][kk] = *(const short8*)(kA + (size_t)(jt * 16) * 64 + kk * 32);
    #pragma unroll
    for (int n = 0; n < 4; ++n)
        vf[n] = *(const short8*)(vB + (size_t)(n * 16) * NN);

    for (int j0k = 0; j0k < NN; j0k += 128) {
        // ---- S^T = K Q^T for this wave's 32 keys (uses prefetched kf)
        floatx4 sT[2][4] = {};
        #pragma unroll
        for (int jt = 0; jt < 2; ++jt)
            #pragma unroll
            for (int c = 0; c < 4; ++c)
                #pragma unroll
                for (int kk = 0; kk < 2; ++kk)
                    sT[jt][c] = __builtin_amdgcn_mfma_f32_16x16x32_bf16(kf[jt][kk], qf[c][kk], sT[jt][c], 0, 0, 0);

        // ---- prefetch next iter's K fragments (latency hidden by softmax/PV)
        const int nxt = j0k + 128;
        if (nxt < NN) {
            #pragma unroll
            for (int jt = 0; jt < 2; ++jt)
                #pragma unroll
                for (int kk = 0; kk < 2; ++kk)
                    kf[jt][kk] = *(const short8*)(kA + (size_t)(nxt + jt * 16) * 64 + kk * 32);
        }

        // ---- P = exp2(S^T); store packed; per-lane l partials
        // lane's element (jt,c,r): query=c*16+fr, key-in-wave=jt*16+fq*4+r
        #pragma unroll
        for (int c = 0; c < 4; ++c) {
            u16* pb = Pw + (c * 16 + fr) * 40;
            #pragma unroll
            for (int jt = 0; jt < 2; ++jt) {
                float p0 = fexp2(sT[jt][c][0]);
                float p1 = fexp2(sT[jt][c][1]);
                float p2 = fexp2(sT[jt][c][2]);
                float p3 = fexp2(sT[jt][c][3]);
                lrun[c] += (p0 + p1) + (p2 + p3);
                uint2 pv = {pack_bf2(p0, p1), pack_bf2(p2, p3)};
                *(uint2*)(pb + jt * 16 + fq * 4) = pv;
            }
        }

        // ---- O_w += P V  (K=32 slice; same-wave LDS, program order suffices)
        short8 pa[4];
        #pragma unroll
        for (int m = 0; m < 4; ++m)
            pa[m] = *(const short8*)(Pw + (m * 16 + fr) * 40 + fq * 8);
        #pragma unroll
        for (int m = 0; m < 4; ++m)
            #pragma unroll
            for (int n = 0; n < 4; ++n)
                o4[m][n] = __builtin_amdgcn_mfma_f32_16x16x32_bf16(pa[m], vf[n], o4[m][n], 0, 0, 0);

        // ---- prefetch next iter's V fragments
        if (nxt < NN) {
            #pragma unroll
            for (int n = 0; n < 4; ++n)
                vf[n] = *(const short8*)(vB + (size_t)(n * 16) * NN + nxt);
        }
    }

    // ---- in-wave l reduce across fq groups (query = c*16 + fr)
    #pragma unroll
    for (int c = 0; c < 4; ++c) {
        lrun[c] += __shfl_xor(lrun[c], 16);
        lrun[c] += __shfl_xor(lrun[c], 32);
    }

    // ---- cross-wave reduction: Ps reused as fp32 scratch [64 q][64 d]
    float* Osc = (float*)Ps;
    __syncthreads();                             // all PV reads of Ps done
    for (int ww = 0; ww < 4; ++ww) {
        if (w == ww) {
            #pragma unroll
            for (int m = 0; m < 4; ++m)
                #pragma unroll
                for (int n = 0; n < 4; ++n)
                    #pragma unroll
                    for (int r = 0; r < 4; ++r) {
                        const int q = m * 16 + fq * 4 + r;
                        const int d = n * 16 + fr;
                        if (ww == 0) Osc[q * 64 + d] = o4[m][n][r];
                        else         Osc[q * 64 + d] += o4[m][n][r];
                    }
            if (fq == 0) {
                #pragma unroll
                for (int c = 0; c < 4; ++c) {
                    const int q = c * 16 + fr;
                    if (ww == 0) Lsc[q] = lrun[c];
                    else         Lsc[q] += lrun[c];
                }
            }
        }
        __syncthreads();
    }

    // ---- normalize + write ctx (B,N,D) bf16
    const int q  = t >> 2;                       // 0..63
    const float inv = 1.0f / Lsc[q];
    #pragma unroll
    for (int i = 0; i < 4; ++i) {
        const int d0 = (t & 3) * 16 + i * 4;
        float4 o = *(const float4*)(Osc + q * 64 + d0);
        us4 u = {f2bf(o.x * inv), f2bf(o.y * inv), f2bf(o.z * inv), f2bf(o.w * inv)};
        *(us4*)&ctx[((size_t)b * NN + q0 + q) * DD + h * 64 + d0] = u;
    }
}

// ---------------------------------------------------------------------------
extern "C" void kernel_launch(void* const* d_in, const int* in_sizes, int n_in,
                              void* d_out, int out_size, void* d_ws, size_t ws_size,
                              hipStream_t stream)
{
    const float* q   = (const float*)d_in[0];
    const float* k   = (const float*)d_in[1];
    const float* v   = (const float*)d_in[2];
    const float* wq  = (const float*)d_in[3];
    const float* wk  = (const float*)d_in[4];
    const float* wv  = (const float*)d_in[5];
    const float* wo  = (const float*)d_in[6];
    const float* rot = (const float*)d_in[7];

    float* out_final = (float*)d_out;            // (B,N,D)
    float* out_kt    = out_final + OUTSZ;        // (B,H,HD,N)
    float* out_vh    = out_kt + OUTSZ;           // (B,H,N,HD)

    u16* wsb  = (u16*)d_ws;
    u16* qb   = wsb;
    u16* kb   = wsb + (size_t) 4 * 1024 * 1024;
    u16* vb   = wsb + (size_t) 8 * 1024 * 1024;
    u16* wqb  = wsb + (size_t)12 * 1024 * 1024;
    u16* wkb  = wsb + (size_t)13 * 1024 * 1024;
    u16* wvb  = wsb + (size_t)14 * 1024 * 1024;
    u16* wob  = wsb + (size_t)15 * 1024 * 1024;
    u16* qhb  = wsb + (size_t)16 * 1024 * 1024;  // (B,H,N,HD), pre-scaled 0.125*log2e
    u16* khb  = wsb + (size_t)20 * 1024 * 1024;  // (B,H,N,HD)
    u16* vtb  = wsb + (size_t)24 * 1024 * 1024;  // (B,H,HD,N)
    u16* ctxb = wsb + (size_t)28 * 1024 * 1024;  // (B,N,D)

    CastArgs ca;
    ca.s[0] = q;  ca.d[0] = qb;  ca.n[0] = OUTSZ;
    ca.s[1] = k;  ca.d[1] = kb;  ca.n[1] = OUTSZ;
    ca.s[2] = v;  ca.d[2] = vb;  ca.n[2] = OUTSZ;
    ca.s[3] = wq; ca.d[3] = wqb; ca.n[3] = DD * DD;
    ca.s[4] = wk; ca.d[4] = wkb; ca.n[4] = DD * DD;
    ca.s[5] = wv; ca.d[5] = wvb; ca.n[5] = DD * DD;
    ca.s[6] = wo; ca.d[6] = wob; ca.n[6] = DD * DD;
    cast_bf16<<<dim3(256, 7), 256, 0, stream>>>(ca);

    ProjArgs pa;
    pa.X[0] = qb;   pa.W[0] = wqb; pa.outf[0] = nullptr;   pa.outb[0] = qhb;
    pa.X[1] = kb;   pa.W[1] = wkb; pa.outf[1] = out_kt;    pa.outb[1] = khb;
    pa.X[2] = vb;   pa.W[2] = wvb; pa.outf[2] = out_vh;    pa.outb[2] = vtb;
    pa.X[3] = ctxb; pa.W[3] = wob; pa.outf[3] = out_final; pa.outb[3] = nullptr;
    pa.rot = rot;

    // fused Q/K/V projections: 768 blocks, 128x128 tiles, BK=64
    mfma_proj<128><<<dim3(DD / 128, (2 * NN) / 128, 3), 256, 0, stream>>>(pa, 0);

    // attention: grid (bh, qtile) so one head pins to one XCD
    mfma_attn<<<dim3(2 * HH, NN / 64), 256, 0, stream>>>(qhb, khb, vtb, ctxb);

    // final projection: 512 blocks (2/CU), 128x64 tiles, BK=64
    mfma_proj<64><<<dim3(DD / 64, (2 * NN) / 128, 1), 256, 0, stream>>>(pa, 3);
}

// Round 8
// 250.506 us; speedup vs baseline: 1.1407x; 1.1407x over previous
//
#include <hip/hip_runtime.h>
#include <math.h>

// (B,N,D,H) = (2,2048,1024,16), HD=64, ROT=32
#define NN 2048
#define DD 1024
#define HH 16
#define OUTSZ (2*NN*DD)

typedef unsigned short u16;
typedef unsigned int u32;
typedef __attribute__((ext_vector_type(8))) short short8;     // 8 bf16 (4 VGPRs)
typedef __attribute__((ext_vector_type(4))) float floatx4;
typedef __attribute__((ext_vector_type(4))) unsigned short us4;

__device__ __forceinline__ u16 f2bf(float x) {
    union { float f; unsigned u; } v; v.f = x;
    unsigned r = v.u + 0x7FFFu + ((v.u >> 16) & 1u);   // RNE
    return (u16)(r >> 16);
}

__device__ __forceinline__ u32 fbits(float x) {
    union { float f; u32 u; } v; v.f = x; return v.u;
}

// pack two fp32 -> two bf16 (round-half-up) in one v_perm
__device__ __forceinline__ u32 pack_bf2(float lo, float hi) {
    return __builtin_amdgcn_perm(fbits(hi) + 0x8000u, fbits(lo) + 0x8000u, 0x07060302u);
}

__device__ __forceinline__ float fexp2(float x) {
#if __has_builtin(__builtin_amdgcn_exp2f)
    return __builtin_amdgcn_exp2f(x);
#else
    return __expf(x * 0.69314718056f);
#endif
}

__device__ __forceinline__ void gl_lds16(const u16* g, u16* l) {
    __builtin_amdgcn_global_load_lds(
        (const __attribute__((address_space(1))) unsigned int*)g,
        (__attribute__((address_space(3))) unsigned int*)l, 16, 0, 0);
}

// ---------------------------------------------------------------------------
// fp32 -> bf16 cast for q,k,v + 4 weights
// ---------------------------------------------------------------------------
struct CastArgs { const float* s[7]; u16* d[7]; int n[7]; };

__global__ __launch_bounds__(256)
void cast_bf16(CastArgs a) {
    const int ten = blockIdx.y;
    const float4* s = (const float4*)a.s[ten];
    us4* d = (us4*)a.d[ten];
    const int n4 = a.n[ten] >> 2;
    for (int i = blockIdx.x * 256 + threadIdx.x; i < n4; i += gridDim.x * 256) {
        float4 f = s[i];
        us4 u = {f2bf(f.x), f2bf(f.y), f2bf(f.z), f2bf(f.w)};
        d[i] = u;
    }
}

// ---------------------------------------------------------------------------
// bf16 MFMA projection GEMM (unchanged from R6): tile 128 x TN, BK=64.
// ---------------------------------------------------------------------------
struct ProjArgs {
    const u16* X[4]; const u16* W[4];
    float* outf[4];  u16* outb[4];
    const float* rot;
};

template<int TN>
__global__ __launch_bounds__(256)
void mfma_proj(ProjArgs a, int mode_base)
{
    constexpr int TNW = TN / 2;      // wave cols
    constexpr int NJ  = TNW / 16;    // B-fragments per wave

    __shared__ __align__(16) u16 As[128 * 64];
    __shared__ __align__(16) u16 Bs[TN * 64];

    const int mode = mode_base + blockIdx.z;
    const u16* __restrict__ X   = a.X[mode];
    const u16* __restrict__ Wm  = a.W[mode];
    float* __restrict__ outf    = a.outf[mode];
    u16* __restrict__ outb      = a.outb[mode];
    const float* __restrict__ rot = a.rot;

    const int t    = threadIdx.x;
    const int lane = t & 63;
    const int w    = t >> 6;
    const int wr   = (w >> 1) * 64;
    const int wc   = (w & 1) * TNW;
    const int m0   = blockIdx.y * 128;
    const int j0   = blockIdx.x * TN;

    const int lc = (t & 7) ^ ((t >> 3) & 7);
    const u16* gA = X  + (size_t)(m0 + (t >> 3)) * DD + lc * 8;
    const u16* gB = Wm + (size_t)(j0 + (t >> 3)) * DD + lc * 8;

    const int fr = lane & 15;
    const int fq = lane >> 4;

    floatx4 acc[4][NJ] = {};

    for (int k0 = 0; k0 < DD; k0 += 64) {
        __syncthreads();
        #pragma unroll
        for (int p = 0; p < 4; ++p)
            gl_lds16(gA + (size_t)(32 * p) * DD + k0, As + (p * 256 + t) * 8);
        #pragma unroll
        for (int p = 0; p < TN / 32; ++p)
            gl_lds16(gB + (size_t)(32 * p) * DD + k0, Bs + (p * 256 + t) * 8);
        __syncthreads();
        #pragma unroll
        for (int kk = 0; kk < 2; ++kk) {
            const int ph = (kk * 4 + fq) ^ (fr & 7);
            short8 af[4], bf[NJ];
            #pragma unroll
            for (int i = 0; i < 4; ++i)
                af[i] = *(const short8*)(As + (wr + i * 16 + fr) * 64 + ph * 8);
            #pragma unroll
            for (int j = 0; j < NJ; ++j)
                bf[j] = *(const short8*)(Bs + (wc + j * 16 + fr) * 64 + ph * 8);
            #pragma unroll
            for (int i = 0; i < 4; ++i)
                #pragma unroll
                for (int j = 0; j < NJ; ++j)
                    acc[i][j] = __builtin_amdgcn_mfma_f32_16x16x32_bf16(af[i], bf[j], acc[i][j], 0, 0, 0);
        }
    }

    const int b = m0 >> 11;
    #pragma unroll
    for (int i = 0; i < 4; ++i) {
        const int mrow  = m0 + wr + i * 16 + fq * 4;   // + r
        const int nbase = mrow & (NN - 1);
        #pragma unroll
        for (int j = 0; j < NJ; ++j) {
            const int col = j0 + wc + j * 16 + fr;
            const int h = col >> 6, d = col & 63;
            const int bh = b * HH + h;
            float v[4];
            #pragma unroll
            for (int r = 0; r < 4; ++r) v[r] = acc[i][j][r];
            // rotary applies to head-dims d<32; d = ((wc+j*16)&63) + fr
            if (mode <= 1 && ((wc + j * 16) & 63) < 32) {
                #pragma unroll
                for (int r = 0; r < 4; ++r) {
                    const int n = nbase + r;
                    float c = v[r];
                    float p = __shfl_xor(c, 1);     // partner element d^1
                    float f = rot[n * 32 + d];
                    float sn, cs; __sincosf(f, &sn, &cs);
                    v[r] = (d & 1) ? fmaf(c, cs, p * sn) : fmaf(c, cs, -p * sn);
                }
            }
            if (mode == 0) {
                // fold softmax scale 1/8 and log2(e) into Q
                #pragma unroll
                for (int r = 0; r < 4; ++r)
                    outb[((size_t)bh * NN + nbase + r) * 64 + d] = f2bf(v[r] * 0.1803368801111244f);
            } else if (mode == 1) {
                float4 f4 = {v[0], v[1], v[2], v[3]};
                *(float4*)&outf[((size_t)bh * 64 + d) * NN + nbase] = f4;
                #pragma unroll
                for (int r = 0; r < 4; ++r)
                    outb[((size_t)bh * NN + nbase + r) * 64 + d] = f2bf(v[r]);
            } else if (mode == 2) {
                #pragma unroll
                for (int r = 0; r < 4; ++r)
                    outf[((size_t)bh * NN + nbase + r) * 64 + d] = v[r];
                us4 u = {f2bf(v[0]), f2bf(v[1]), f2bf(v[2]), f2bf(v[3])};
                *(us4*)&outb[((size_t)bh * 64 + d) * NN + nbase] = u;
            } else {
                #pragma unroll
                for (int r = 0; r < 4; ++r)
                    outf[(size_t)(mrow + r) * DD + col] = v[r];
            }
        }
    }
}

// ---------------------------------------------------------------------------
// bf16 MFMA flash attention, hybrid staging.
// Block = (b,h) x 64 queries; grid (bh, qtile): same-head blocks pin to one
// XCD (stride 32 % 8 == 0) -> K/V L2-resident (R6: FETCH 12 MB).
// V (shared by all 4 waves) staged via global_load_lds, barrier-pipelined --
// only 4 DMAs/iter (half of R6's drain). K (wave-private 32 keys) loads
// directly global->VGPR, double-buffered: kn issued right after the V
// barrier; next iter's barrier drain enforces completion ~600 cyc later.
// P via per-wave LDS (program order, no barrier). LDS 36.3 KB.
// ---------------------------------------------------------------------------
__global__ __launch_bounds__(256, 3)
void mfma_attn(const u16* __restrict__ qh, const u16* __restrict__ kh,
               const u16* __restrict__ vt, u16* __restrict__ ctx)
{
    __shared__ __align__(16) u16 Vs[64 * 128];   // [hd][key], 256-B rows, 16 KB
    __shared__ __align__(16) u16 Ps[4 * 64 * 40];// per-wave P, 80-B rows, 20 KB
    __shared__ float Lsc[64];

    const int t    = threadIdx.x;
    const int lane = t & 63;
    const int w    = t >> 6;
    const int fr   = lane & 15;
    const int fq   = lane >> 4;
    const int bh   = blockIdx.x;
    const int q0   = blockIdx.y * 64;
    const int b    = bh >> 4, h = bh & 15;

    // Q: all 64 queries per wave (B-frag: n=query=fr, k=kk*32+fq*8)
    short8 qf[4][2];
    #pragma unroll
    for (int c = 0; c < 4; ++c)
        #pragma unroll
        for (int kk = 0; kk < 2; ++kk)
            qf[c][kk] = *(const short8*)(qh +
                ((size_t)bh * NN + q0 + c * 16 + fr) * 64 + kk * 32 + fq * 8);

    // K A-frag base: row = j0k + w*32 + jt*16 + fr, k-chunk = kk*32 + fq*8
    const u16* kA = kh + ((size_t)bh * NN + w * 32 + fr) * 64 + fq * 8;
    // V staging (same as R6): 64 rows x 256 B, chunk16 XOR swizzle
    const int lc16 = (t & 15) ^ ((t >> 4) & 15);
    const u16* vg = vt + ((size_t)bh * 64 + (t >> 4)) * NN + lc16 * 8;

    u16* Pw = Ps + w * 64 * 40;                  // this wave's 64q x 32k tile
    const int psw = 2 * (fr & 7);                // sub-chunk swizzle mask

    floatx4 o4[4][4] = {};                       // [query m-tile][d n-tile]
    float lrun[4] = {0.f, 0.f, 0.f, 0.f};

    // prefetch iter-0 K fragments
    short8 kf[2][2];
    #pragma unroll
    for (int jt = 0; jt < 2; ++jt)
        #pragma unroll
        for (int kk = 0; kk < 2; ++kk)
            kf[jt][kk] = *(const short8*)(kA + (size_t)(jt * 16) * 64 + kk * 32);

    for (int j0k = 0; j0k < NN; j0k += 128) {
        __syncthreads();                         // prev iter's Vs/Ps reads done
        #pragma unroll
        for (int p = 0; p < 4; ++p)
            gl_lds16(vg + (size_t)(p * 16) * NN + j0k, Vs + (p * 256 + t) * 8);
        __syncthreads();                         // V ready (drains kn too)

        // ---- issue next iter's K loads NOW (branch-free wrap on last iter);
        // completion enforced by the NEXT iteration's barrier drain.
        const int nxt = (j0k + 128) & (NN - 1);
        short8 kn[2][2];
        #pragma unroll
        for (int jt = 0; jt < 2; ++jt)
            #pragma unroll
            for (int kk = 0; kk < 2; ++kk)
                kn[jt][kk] = *(const short8*)(kA + (size_t)(nxt + jt * 16) * 64 + kk * 32);

        // ---- S^T = K Q^T for this wave's 32 keys
        floatx4 sT[2][4] = {};
        #pragma unroll
        for (int jt = 0; jt < 2; ++jt)
            #pragma unroll
            for (int c = 0; c < 4; ++c)
                #pragma unroll
                for (int kk = 0; kk < 2; ++kk)
                    sT[jt][c] = __builtin_amdgcn_mfma_f32_16x16x32_bf16(kf[jt][kk], qf[c][kk], sT[jt][c], 0, 0, 0);

        // ---- P = exp2(S^T); store packed; per-lane l partials
        // lane's element (jt,c,r): query=c*16+fr, key-in-wave=jt*16+fq*4+r
        #pragma unroll
        for (int c = 0; c < 4; ++c) {
            u16* pb = Pw + (c * 16 + fr) * 40;
            #pragma unroll
            for (int jt = 0; jt < 2; ++jt) {
                float p0 = fexp2(sT[jt][c][0]);
                float p1 = fexp2(sT[jt][c][1]);
                float p2 = fexp2(sT[jt][c][2]);
                float p3 = fexp2(sT[jt][c][3]);
                lrun[c] += (p0 + p1) + (p2 + p3);
                uint2 pv = {pack_bf2(p0, p1), pack_bf2(p2, p3)};
                *(uint2*)(pb + jt * 16 + fq * 4) = pv;
            }
        }

        // ---- O_w += P V  (K=32 slice; same-wave LDS, program order suffices)
        short8 pa[4], vf[4];
        #pragma unroll
        for (int m = 0; m < 4; ++m)
            pa[m] = *(const short8*)(Pw + (m * 16 + fr) * 40 + fq * 8);
        #pragma unroll
        for (int n = 0; n < 4; ++n) {
            const int row = n * 16 + fr;                 // d
            const int phys = (w * 4 + fq) ^ (row & 15);
            vf[n] = *(const short8*)(Vs + row * 128 + phys * 8);
        }
        #pragma unroll
        for (int m = 0; m < 4; ++m)
            #pragma unroll
            for (int n = 0; n < 4; ++n)
                o4[m][n] = __builtin_amdgcn_mfma_f32_16x16x32_bf16(pa[m], vf[n], o4[m][n], 0, 0, 0);

        // ---- rotate K double-buffer
        #pragma unroll
        for (int jt = 0; jt < 2; ++jt)
            #pragma unroll
            for (int kk = 0; kk < 2; ++kk)
                kf[jt][kk] = kn[jt][kk];
    }

    // ---- in-wave l reduce across fq groups (query = c*16 + fr)
    #pragma unroll
    for (int c = 0; c < 4; ++c) {
        lrun[c] += __shfl_xor(lrun[c], 16);
        lrun[c] += __shfl_xor(lrun[c], 32);
    }

    // ---- cross-wave reduction: Ps reused as fp32 scratch [64 q][64 d]
    float* Osc = (float*)Ps;
    __syncthreads();                             // all PV reads of Ps done
    for (int ww = 0; ww < 4; ++ww) {
        if (w == ww) {
            #pragma unroll
            for (int m = 0; m < 4; ++m)
                #pragma unroll
                for (int n = 0; n < 4; ++n)
                    #pragma unroll
                    for (int r = 0; r < 4; ++r) {
                        const int q = m * 16 + fq * 4 + r;
                        const int d = n * 16 + fr;
                        if (ww == 0) Osc[q * 64 + d] = o4[m][n][r];
                        else         Osc[q * 64 + d] += o4[m][n][r];
                    }
            if (fq == 0) {
                #pragma unroll
                for (int c = 0; c < 4; ++c) {
                    const int q = c * 16 + fr;
                    if (ww == 0) Lsc[q] = lrun[c];
                    else         Lsc[q] += lrun[c];
                }
            }
        }
        __syncthreads();
    }

    // ---- normalize + write ctx (B,N,D) bf16
    const int q  = t >> 2;                       // 0..63
    const float inv = 1.0f / Lsc[q];
    #pragma unroll
    for (int i = 0; i < 4; ++i) {
        const int d0 = (t & 3) * 16 + i * 4;
        float4 o = *(const float4*)(Osc + q * 64 + d0);
        us4 u = {f2bf(o.x * inv), f2bf(o.y * inv), f2bf(o.z * inv), f2bf(o.w * inv)};
        *(us4*)&ctx[((size_t)b * NN + q0 + q) * DD + h * 64 + d0] = u;
    }
}

// ---------------------------------------------------------------------------
extern "C" void kernel_launch(void* const* d_in, const int* in_sizes, int n_in,
                              void* d_out, int out_size, void* d_ws, size_t ws_size,
                              hipStream_t stream)
{
    const float* q   = (const float*)d_in[0];
    const float* k   = (const float*)d_in[1];
    const float* v   = (const float*)d_in[2];
    const float* wq  = (const float*)d_in[3];
    const float* wk  = (const float*)d_in[4];
    const float* wv  = (const float*)d_in[5];
    const float* wo  = (const float*)d_in[6];
    const float* rot = (const float*)d_in[7];

    float* out_final = (float*)d_out;            // (B,N,D)
    float* out_kt    = out_final + OUTSZ;        // (B,H,HD,N)
    float* out_vh    = out_kt + OUTSZ;           // (B,H,N,HD)

    u16* wsb  = (u16*)d_ws;
    u16* qb   = wsb;
    u16* kb   = wsb + (size_t) 4 * 1024 * 1024;
    u16* vb   = wsb + (size_t) 8 * 1024 * 1024;
    u16* wqb  = wsb + (size_t)12 * 1024 * 1024;
    u16* wkb  = wsb + (size_t)13 * 1024 * 1024;
    u16* wvb  = wsb + (size_t)14 * 1024 * 1024;
    u16* wob  = wsb + (size_t)15 * 1024 * 1024;
    u16* qhb  = wsb + (size_t)16 * 1024 * 1024;  // (B,H,N,HD), pre-scaled 0.125*log2e
    u16* khb  = wsb + (size_t)20 * 1024 * 1024;  // (B,H,N,HD)
    u16* vtb  = wsb + (size_t)24 * 1024 * 1024;  // (B,H,HD,N)
    u16* ctxb = wsb + (size_t)28 * 1024 * 1024;  // (B,N,D)

    CastArgs ca;
    ca.s[0] = q;  ca.d[0] = qb;  ca.n[0] = OUTSZ;
    ca.s[1] = k;  ca.d[1] = kb;  ca.n[1] = OUTSZ;
    ca.s[2] = v;  ca.d[2] = vb;  ca.n[2] = OUTSZ;
    ca.s[3] = wq; ca.d[3] = wqb; ca.n[3] = DD * DD;
    ca.s[4] = wk; ca.d[4] = wkb; ca.n[4] = DD * DD;
    ca.s[5] = wv; ca.d[5] = wvb; ca.n[5] = DD * DD;
    ca.s[6] = wo; ca.d[6] = wob; ca.n[6] = DD * DD;
    cast_bf16<<<dim3(256, 7), 256, 0, stream>>>(ca);

    ProjArgs pa;
    pa.X[0] = qb;   pa.W[0] = wqb; pa.outf[0] = nullptr;   pa.outb[0] = qhb;
    pa.X[1] = kb;   pa.W[1] = wkb; pa.outf[1] = out_kt;    pa.outb[1] = khb;
    pa.X[2] = vb;   pa.W[2] = wvb; pa.outf[2] = out_vh;    pa.outb[2] = vtb;
    pa.X[3] = ctxb; pa.W[3] = wob; pa.outf[3] = out_final; pa.outb[3] = nullptr;
    pa.rot = rot;

    // fused Q/K/V projections: 768 blocks, 128x128 tiles, BK=64
    mfma_proj<128><<<dim3(DD / 128, (2 * NN) / 128, 3), 256, 0, stream>>>(pa, 0);

    // attention: grid (bh, qtile) so one head pins to one XCD
    mfma_attn<<<dim3(2 * HH, NN / 64), 256, 0, stream>>>(qhb, khb, vtb, ctxb);

    // final projection: 512 blocks (2/CU), 128x64 tiles, BK=64
    mfma_proj<64><<<dim3(DD / 64, (2 * NN) / 128, 1), 256, 0, stream>>>(pa, 3);
}